// Round 4
// baseline (752.716 us; speedup 1.0000x reference)
//
#include <hip/hip_runtime.h>
#include <hip/hip_bf16.h>

typedef __attribute__((ext_vector_type(8))) short short8;
typedef __attribute__((ext_vector_type(4))) float floatx4;

#define IN_DIM  4096
#define OUT_DIM 4096
#define MROWS   16384
#define GSIZE   128

template <int N> struct IC { static constexpr int value = N; };

__device__ __forceinline__ unsigned short f2bf(float f) {
    unsigned int u = __builtin_bit_cast(unsigned int, f);
    u = (u + 0x7fffu + ((u >> 16) & 1u)) >> 16;
    return (unsigned short)u;
}

#define GLD16(gsrc, ldst)                                                     \
    __builtin_amdgcn_global_load_lds(                                         \
        (const __attribute__((address_space(1))) unsigned int*)(const void*)(gsrc), \
        (__attribute__((address_space(3))) unsigned int*)(void*)(ldst),       \
        16, 0, 0)

// ---------------------------------------------------------------- convert x
__global__ void convert_x(const float* __restrict__ x,
                          unsigned short* __restrict__ xb, int n8) {
    int stride = gridDim.x * blockDim.x;
    for (int i = blockIdx.x * blockDim.x + threadIdx.x; i < n8; i += stride) {
        const float4* xf = (const float4*)x;
        float4 f0 = xf[2 * i];
        float4 f1 = xf[2 * i + 1];
        union { unsigned short u[8]; uint4 v; } pk;
        pk.u[0] = f2bf(f0.x); pk.u[1] = f2bf(f0.y);
        pk.u[2] = f2bf(f0.z); pk.u[3] = f2bf(f0.w);
        pk.u[4] = f2bf(f1.x); pk.u[5] = f2bf(f1.y);
        pk.u[6] = f2bf(f1.z); pk.u[7] = f2bf(f1.w);
        ((uint4*)xb)[i] = pk.v;
    }
}

// ---------------------------------------------------------------- decode W
__global__ void decode_w(const int* __restrict__ pw,
                         const float* __restrict__ norms,
                         const float* __restrict__ s1,
                         const float* __restrict__ s2,
                         const float* __restrict__ cent,
                         unsigned short* __restrict__ W) {
    int row  = blockIdx.x * 4 + (threadIdx.x >> 6);
    int lane = threadIdx.x & 63;
    float nrm = norms[row];
    int c0 = pw[(size_t)row * GSIZE + lane];
    int c1 = pw[(size_t)row * GSIZE + lane + 64];
    float e0 = cent[c0] * nrm * s2[lane];
    float e1 = cent[c1] * nrm * s2[lane + 64];
#pragma unroll
    for (int it = 0; it < 7; ++it) {
        float a = e0, b = e1;
        e0 = a + b;
        e1 = a - b;
    }
    const float inv = 0.08838834764831845f; // 1/sqrt(128)
    int o = row >> 5, g = row & 31;
    unsigned short* wr = W + (size_t)o * IN_DIM + g * GSIZE;
    wr[lane]      = f2bf(e0 * inv * s1[lane]);
    wr[lane + 64] = f2bf(e1 * inv * s1[lane + 64]);
}

// ---------------------------------------------------------------- GEMM
// 256x256 tile, BK=64, 8 waves (2M x 4N), m201-style 8-phase schedule
// (4 phases per K-tile, 16 MFMA/phase/wave), counted vmcnt(6), half-tile
// staging one per phase.
//
// Regions (per buf): B0 = B rows[0,128), B1 = B rows[128,256),
//   A0 = A rows[0,64)u[128,192) (m-frags 0-3), A1 = rows[64,128)u[192,256).
// Phase p reads A m=2p,2p+1 (and all B at p0); end-barrier of p certifies
// those reads complete -> staging that region afterwards is safe.
// Stage plan at tile j (buf BF=j&1): p0: A1(j+1)->BF^1 (read at p2,p3 of
// j-1), p1: B0(j+2)->BF (read p0), p2: A0(j+2)->BF (read p0,p1),
// p3: B1(j+2)->BF (read p0).
// vmcnt(6) at p3(j): 6 newest loads = B0/A0/B1(j+2) -> certifies A1(j+1)
// and everything older landed; mid-barrier globalizes => tile j+1 fully
// resident before p0(j+1). Oldest waited load issued >=3 phases earlier.
__global__ __launch_bounds__(512, 2)
void gemm_bf16(const unsigned short* __restrict__ Xg,
               const unsigned short* __restrict__ Wg,
               const float* __restrict__ bias,
               float* __restrict__ out) {
    __shared__ unsigned short As[2][256][64];
    __shared__ unsigned short Bs[2][256][64];

    // bijective XCD swizzle (1024 blocks % 8 == 0)
    int id = (blockIdx.x & 7) * 128 + (blockIdx.x >> 3);
    int mt = id >> 4, nt = id & 15;
    int m0 = mt * 256, n0 = nt * 256;

    int tid  = threadIdx.x;
    int lane = tid & 63;
    int wid  = tid >> 6;
    int wm = wid >> 2, wn = wid & 3;   // wave tile: rows wm*128+, cols wn*64+

    // staging: thread handles 16B phys chunk cp0 of rows (base + tid>>3)
    // LDS dest is linear in tid (wave-uniform base + lane*16)  [m104-safe]
    int sr0 = tid >> 3;        // 0..63
    int cp0 = tid & 7;         // physical chunk position
    int sg0 = cp0 ^ (sr0 & 7); // global chunk (inverse swizzle)

#define STG_BH(bufc, h, j) do {                                               \
    const unsigned short* _s =                                                \
        Wg + (size_t)(n0 + (h)*128 + sr0) * IN_DIM + (size_t)(j)*64 + sg0*8;  \
    GLD16(_s,                &Bs[bufc][(h)*128 + sr0][cp0 * 8]);              \
    GLD16(_s + 64 * IN_DIM,  &Bs[bufc][(h)*128 + sr0 + 64][cp0 * 8]);         \
  } while (0)
#define STG_AH(bufc, h, j) do {                                               \
    const unsigned short* _s =                                                \
        Xg + (size_t)(m0 + (h)*64 + sr0) * IN_DIM + (size_t)(j)*64 + sg0*8;   \
    GLD16(_s,                 &As[bufc][(h)*64 + sr0][cp0 * 8]);              \
    GLD16(_s + 128 * IN_DIM,  &As[bufc][128 + (h)*64 + sr0][cp0 * 8]);        \
  } while (0)

    int rl = lane & 15, kc = lane >> 4;
    short8 a_[2][2], b_[4][2];
    floatx4 acc[8][4] = {};

#define LD_A(BFc, mm, m, ks) do {                                             \
    int row_ = wm * 128 + (m)*16 + rl;                                        \
    a_[mm][ks] = *(const short8*)&As[BFc][row_][((((ks)*4 + kc) ^ (row_ & 7)) << 3)]; \
  } while (0)
#define LD_B(BFc, n, ks) do {                                                 \
    int row_ = wn * 64 + (n)*16 + rl;                                         \
    b_[n][ks] = *(const short8*)&Bs[BFc][row_][((((ks)*4 + kc) ^ (row_ & 7)) << 3)]; \
  } while (0)

#define MIDBAR() do { __builtin_amdgcn_sched_barrier(0);                      \
                      __builtin_amdgcn_s_barrier(); } while (0)
#define LGKM0()  do { asm volatile("s_waitcnt lgkmcnt(0)" ::: "memory");      \
                      __builtin_amdgcn_sched_barrier(0); } while (0)
#define ENDBAR() do { __builtin_amdgcn_sched_barrier(0);                      \
                      __builtin_amdgcn_s_barrier(); } while (0)

#define MFMA_P(p) do {                                                        \
    __builtin_amdgcn_s_setprio(1);                                            \
    _Pragma("unroll") for (int ks = 0; ks < 2; ++ks) {                        \
      _Pragma("unroll") for (int mm = 0; mm < 2; ++mm) {                      \
        _Pragma("unroll") for (int n = 0; n < 4; ++n)                         \
          acc[2*(p)+mm][n] = __builtin_amdgcn_mfma_f32_16x16x32_bf16(         \
              a_[mm][ks], b_[n][ks], acc[2*(p)+mm][n], 0, 0, 0);              \
      }                                                                       \
    }                                                                         \
    __builtin_amdgcn_s_setprio(0);                                            \
  } while (0)

    // ---- prologue: tile0 fully (8 loads), then B0,A0,B1 of tile1 (6 loads)
    STG_BH(0, 0, 0); STG_AH(0, 0, 0); STG_BH(0, 1, 0); STG_AH(0, 1, 0);
    STG_BH(1, 0, 1); STG_AH(1, 0, 1); STG_BH(1, 1, 1);
    asm volatile("s_waitcnt vmcnt(6)" ::: "memory");  // tile0 resident
    __builtin_amdgcn_s_barrier();

    // MODE: 2 = steady, 1 = stage only A1(j+1) + vmcnt(0), 0 = nothing
    auto body = [&](int j, auto bfc, auto modec) {
        constexpr int BF   = decltype(bfc)::value;
        constexpr int MODE = decltype(modec)::value;
        // ---- p0: all B + A m0,m1; stage A1(j+1) into other buf
        LD_B(BF, 0, 0); LD_B(BF, 0, 1); LD_B(BF, 1, 0); LD_B(BF, 1, 1);
        LD_B(BF, 2, 0); LD_B(BF, 2, 1); LD_B(BF, 3, 0); LD_B(BF, 3, 1);
        LD_A(BF, 0, 0, 0); LD_A(BF, 0, 0, 1);
        LD_A(BF, 1, 1, 0); LD_A(BF, 1, 1, 1);
        if constexpr (MODE >= 1) STG_AH(BF ^ 1, 1, j + 1);
        MIDBAR(); LGKM0();
        MFMA_P(0);
        ENDBAR();
        // ---- p1: A m2,m3; stage B0(j+2)
        LD_A(BF, 0, 2, 0); LD_A(BF, 0, 2, 1);
        LD_A(BF, 1, 3, 0); LD_A(BF, 1, 3, 1);
        if constexpr (MODE == 2) STG_BH(BF, 0, j + 2);
        MIDBAR(); LGKM0();
        MFMA_P(1);
        ENDBAR();
        // ---- p2: A m4,m5; stage A0(j+2)
        LD_A(BF, 0, 4, 0); LD_A(BF, 0, 4, 1);
        LD_A(BF, 1, 5, 0); LD_A(BF, 1, 5, 1);
        if constexpr (MODE == 2) STG_AH(BF, 0, j + 2);
        MIDBAR(); LGKM0();
        MFMA_P(2);
        ENDBAR();
        // ---- p3: A m6,m7; stage B1(j+2); counted vmcnt
        LD_A(BF, 0, 6, 0); LD_A(BF, 0, 6, 1);
        LD_A(BF, 1, 7, 0); LD_A(BF, 1, 7, 1);
        if constexpr (MODE == 2) {
            STG_BH(BF, 1, j + 2);
            asm volatile("s_waitcnt vmcnt(6)" ::: "memory"); // tile j+1 landed
        } else if constexpr (MODE == 1) {
            asm volatile("s_waitcnt vmcnt(0)" ::: "memory");
        }
        MIDBAR(); LGKM0();
        MFMA_P(3);
        ENDBAR();
    };

    for (int j = 0; j < 62; j += 2) {
        body(j,     IC<0>{}, IC<2>{});
        body(j + 1, IC<1>{}, IC<2>{});
    }
    body(62, IC<0>{}, IC<1>{});
    body(63, IC<1>{}, IC<0>{});

    // ---- epilogue: C/D layout col = lane&15, row = (lane>>4)*4 + i
    int q = lane >> 4;
#pragma unroll
    for (int n = 0; n < 4; ++n) {
        int col = n0 + wn * 64 + n * 16 + rl;
        float bv = bias[col];
#pragma unroll
        for (int m = 0; m < 8; ++m) {
#pragma unroll
            for (int i = 0; i < 4; ++i) {
                int row = m0 + wm * 128 + m * 16 + q * 4 + i;
                out[(size_t)row * OUT_DIM + col] = acc[m][n][i] + bv;
            }
        }
    }
#undef STG_AH
#undef STG_BH
#undef LD_A
#undef LD_B
#undef MIDBAR
#undef LGKM0
#undef ENDBAR
#undef MFMA_P
}

// ---------------------------------------------------------------- launch
extern "C" void kernel_launch(void* const* d_in, const int* in_sizes, int n_in,
                              void* d_out, int out_size, void* d_ws, size_t ws_size,
                              hipStream_t stream) {
    const float* x     = (const float*)d_in[0];
    const int*   pw    = (const int*)d_in[1];
    const float* norms = (const float*)d_in[2];
    const float* s1    = (const float*)d_in[3];
    const float* s2    = (const float*)d_in[4];
    const float* cent  = (const float*)d_in[5];
    const float* bias  = (const float*)d_in[6];
    float* out = (float*)d_out;

    size_t needX = (size_t)MROWS * IN_DIM * 2;    // 128 MB
    size_t needW = (size_t)OUT_DIM * IN_DIM * 2;  //  32 MB
    if (ws_size < needX + needW) return;

    unsigned short* Xb = (unsigned short*)d_ws;
    unsigned short* Wb = (unsigned short*)((char*)d_ws + needX);

    convert_x<<<2048, 256, 0, stream>>>(x, Xb, MROWS * IN_DIM / 8);
    decode_w<<<(OUT_DIM * 32) / 4, 256, 0, stream>>>(pw, norms, s1, s2, cent, Wb);
    gemm_bf16<<<(MROWS / 256) * (OUT_DIM / 256), 512, 0, stream>>>(Xb, Wb, bias, out);
}

// Round 5
// 676.874 us; speedup vs baseline: 1.1120x; 1.1120x over previous
//
#include <hip/hip_runtime.h>
#include <hip/hip_bf16.h>

typedef __attribute__((ext_vector_type(8))) short short8;
typedef __attribute__((ext_vector_type(4))) float floatx4;

#define IN_DIM  4096
#define OUT_DIM 4096
#define MROWS   16384
#define GSIZE   128

template <int N> struct IC { static constexpr int value = N; };

__device__ __forceinline__ unsigned short f2bf(float f) {
    unsigned int u = __builtin_bit_cast(unsigned int, f);
    u = (u + 0x7fffu + ((u >> 16) & 1u)) >> 16;
    return (unsigned short)u;
}

#define GLD16(gsrc, ldst)                                                     \
    __builtin_amdgcn_global_load_lds(                                         \
        (const __attribute__((address_space(1))) unsigned int*)(const void*)(gsrc), \
        (__attribute__((address_space(3))) unsigned int*)(void*)(ldst),       \
        16, 0, 0)

// ---------------------------------------------------------------- convert x
__global__ void convert_x(const float* __restrict__ x,
                          unsigned short* __restrict__ xb, int n8) {
    int stride = gridDim.x * blockDim.x;
    for (int i = blockIdx.x * blockDim.x + threadIdx.x; i < n8; i += stride) {
        const float4* xf = (const float4*)x;
        float4 f0 = xf[2 * i];
        float4 f1 = xf[2 * i + 1];
        union { unsigned short u[8]; uint4 v; } pk;
        pk.u[0] = f2bf(f0.x); pk.u[1] = f2bf(f0.y);
        pk.u[2] = f2bf(f0.z); pk.u[3] = f2bf(f0.w);
        pk.u[4] = f2bf(f1.x); pk.u[5] = f2bf(f1.y);
        pk.u[6] = f2bf(f1.z); pk.u[7] = f2bf(f1.w);
        ((uint4*)xb)[i] = pk.v;
    }
}

// ---------------------------------------------------------------- decode W
__global__ void decode_w(const int* __restrict__ pw,
                         const float* __restrict__ norms,
                         const float* __restrict__ s1,
                         const float* __restrict__ s2,
                         const float* __restrict__ cent,
                         unsigned short* __restrict__ W) {
    int row  = blockIdx.x * 4 + (threadIdx.x >> 6);
    int lane = threadIdx.x & 63;
    float nrm = norms[row];
    int c0 = pw[(size_t)row * GSIZE + lane];
    int c1 = pw[(size_t)row * GSIZE + lane + 64];
    float e0 = cent[c0] * nrm * s2[lane];
    float e1 = cent[c1] * nrm * s2[lane + 64];
#pragma unroll
    for (int it = 0; it < 7; ++it) {
        float a = e0, b = e1;
        e0 = a + b;
        e1 = a - b;
    }
    const float inv = 0.08838834764831845f; // 1/sqrt(128)
    int o = row >> 5, g = row & 31;
    unsigned short* wr = W + (size_t)o * IN_DIM + g * GSIZE;
    wr[lane]      = f2bf(e0 * inv * s1[lane]);
    wr[lane + 64] = f2bf(e1 * inv * s1[lane + 64]);
}

// ---------------------------------------------------------------- GEMM
// 256x256 tile, BK=64, 8 waves (2M x 4N). Phase-level software pipeline:
// every ds_read slice is issued one phase before its MFMA consumes it, so
// the LDS drain hides under the other slice's MFMA. 2 barriers/K-tile,
// zero hot waits.
//
// Per K-tile kt (BF = kt&1):
//  p0: issue ds_read ks1(kt) [BF, 12]; MFMA ks0(kt) (operands from
//      p1(kt-1); compiler inserts counted lgkm); then vmcnt(0) [tile kt+1
//      loads, issued p1(kt-1) = ~2 MFMA phases ago -> cold] + barrier b2.
//  p1: issue ds_read ks0(kt+1) [BF^1, 12]; lgkmcnt(12) [= my ks1(kt) reads
//      of BF done AND ks1 operand cert]; barrier b1 [global: BF free];
//      STG(kt+2 -> BF) [8 global_load_lds, HBM latency hides under MFMA];
//      MFMA ks1(kt).
__global__ __launch_bounds__(512, 2)
void gemm_bf16(const unsigned short* __restrict__ Xg,
               const unsigned short* __restrict__ Wg,
               const float* __restrict__ bias,
               float* __restrict__ out) {
    __shared__ unsigned short As[2][256][64];
    __shared__ unsigned short Bs[2][256][64];

    // bijective XCD swizzle (1024 blocks % 8 == 0); consecutive ids share mt
    int id = (blockIdx.x & 7) * 128 + (blockIdx.x >> 3);
    int mt = id >> 4, nt = id & 15;
    int m0 = mt * 256, n0 = nt * 256;

    int tid  = threadIdx.x;
    int lane = tid & 63;
    int wid  = tid >> 6;
    int wm = wid >> 2, wn = wid & 3;   // wave tile: rows wm*128+, cols wn*64+

    // staging: thread handles 16B phys chunk cp0 of rows sr0 / sr0+64
    int sr0 = tid >> 3;        // 0..63
    int cp0 = tid & 7;         // physical chunk position
    int sg0 = cp0 ^ (sr0 & 7); // global chunk (inverse swizzle)

#define STG_A(bufc, h, j) do {                                                \
    const unsigned short* _s =                                                \
        Xg + (size_t)(m0 + (h)*128 + sr0) * IN_DIM + (size_t)(j)*64 + sg0*8;  \
    GLD16(_s,                &As[bufc][(h)*128 + sr0][cp0 * 8]);              \
    GLD16(_s + 64 * IN_DIM,  &As[bufc][(h)*128 + sr0 + 64][cp0 * 8]);         \
  } while (0)
#define STG_B(bufc, h, j) do {                                                \
    const unsigned short* _s =                                                \
        Wg + (size_t)(n0 + (h)*128 + sr0) * IN_DIM + (size_t)(j)*64 + sg0*8;  \
    GLD16(_s,                &Bs[bufc][(h)*128 + sr0][cp0 * 8]);              \
    GLD16(_s + 64 * IN_DIM,  &Bs[bufc][(h)*128 + sr0 + 64][cp0 * 8]);         \
  } while (0)
#define STG_TILE(bufc, j) do {                                                \
    STG_B(bufc, 0, j); STG_B(bufc, 1, j);                                     \
    STG_A(bufc, 0, j); STG_A(bufc, 1, j);                                     \
  } while (0)

    int rl = lane & 15, kc = lane >> 4;
    short8 a_[8][2], b_[4][2];
    floatx4 acc[8][4] = {};

#define LD_A(BFc, m, ks) do {                                                 \
    int row_ = wm * 128 + (m)*16 + rl;                                        \
    a_[m][ks] = *(const short8*)&As[BFc][row_][((((ks)*4 + kc) ^ (row_ & 7)) << 3)]; \
  } while (0)
#define LD_B(BFc, n, ks) do {                                                 \
    int row_ = wn * 64 + (n)*16 + rl;                                         \
    b_[n][ks] = *(const short8*)&Bs[BFc][row_][((((ks)*4 + kc) ^ (row_ & 7)) << 3)]; \
  } while (0)
#define LD_SLICE(BFc, ks) do {                                                \
    LD_B(BFc, 0, ks); LD_B(BFc, 1, ks); LD_B(BFc, 2, ks); LD_B(BFc, 3, ks);   \
    LD_A(BFc, 0, ks); LD_A(BFc, 1, ks); LD_A(BFc, 2, ks); LD_A(BFc, 3, ks);   \
    LD_A(BFc, 4, ks); LD_A(BFc, 5, ks); LD_A(BFc, 6, ks); LD_A(BFc, 7, ks);   \
  } while (0)

#define MFMA_KS(ks) do {                                                      \
    __builtin_amdgcn_s_setprio(1);                                            \
    _Pragma("unroll") for (int m = 0; m < 8; ++m) {                           \
      _Pragma("unroll") for (int n = 0; n < 4; ++n)                           \
        acc[m][n] = __builtin_amdgcn_mfma_f32_16x16x32_bf16(                  \
            a_[m][ks], b_[n][ks], acc[m][n], 0, 0, 0);                        \
    }                                                                         \
    __builtin_amdgcn_s_setprio(0);                                            \
  } while (0)

    // ---- prologue: stage tiles 0,1; certify tile0; preload ks0(0)
    STG_TILE(0, 0);
    STG_TILE(1, 1);
    asm volatile("s_waitcnt vmcnt(8)" ::: "memory");  // tile0 resident
    __builtin_amdgcn_s_barrier();
    LD_SLICE(0, 0);

    // MODE: 2 steady; 1 = kt=62 (no STG); 0 = kt=63 (tail, no next reads)
    auto body = [&](int kt, auto bfc, auto modec) {
        constexpr int BF   = decltype(bfc)::value;
        constexpr int MODE = decltype(modec)::value;
        // ---- p0: issue next-slice reads; MFMA current slice; cold vmcnt
        LD_SLICE(BF, 1);
        __builtin_amdgcn_sched_barrier(0);
        MFMA_KS(0);
        if constexpr (MODE >= 1) {
            __builtin_amdgcn_sched_barrier(0);
            asm volatile("s_waitcnt vmcnt(0)" ::: "memory"); // tile kt+1 landed
            __builtin_amdgcn_sched_barrier(0);
            __builtin_amdgcn_s_barrier();                    // b2
        }
        // ---- p1: issue next-tile ks0 reads; WAR cert; stage kt+2; MFMA ks1
        if constexpr (MODE >= 1) {
            LD_SLICE(BF ^ 1, 0);
            asm volatile("s_waitcnt lgkmcnt(12)" ::: "memory"); // BF reads done
            __builtin_amdgcn_sched_barrier(0);
            __builtin_amdgcn_s_barrier();                       // b1
        } else {
            asm volatile("s_waitcnt lgkmcnt(0)" ::: "memory");
            __builtin_amdgcn_sched_barrier(0);
        }
        if constexpr (MODE == 2) STG_TILE(BF, kt + 2);
        MFMA_KS(1);
    };

    for (int kt = 0; kt < 62; kt += 2) {
        body(kt,     IC<0>{}, IC<2>{});
        body(kt + 1, IC<1>{}, IC<2>{});
    }
    body(62, IC<0>{}, IC<1>{});
    body(63, IC<1>{}, IC<0>{});

    // ---- epilogue: C/D layout col = lane&15, row = (lane>>4)*4 + i
    int q = lane >> 4;
#pragma unroll
    for (int n = 0; n < 4; ++n) {
        int col = n0 + wn * 64 + n * 16 + rl;
        float bv = bias[col];
#pragma unroll
        for (int m = 0; m < 8; ++m) {
#pragma unroll
            for (int i = 0; i < 4; ++i) {
                int row = m0 + wm * 128 + m * 16 + q * 4 + i;
                out[(size_t)row * OUT_DIM + col] = acc[m][n][i] + bv;
            }
        }
    }
#undef STG_A
#undef STG_B
#undef STG_TILE
#undef LD_A
#undef LD_B
#undef LD_SLICE
#undef MFMA_KS
}

// ---------------------------------------------------------------- launch
extern "C" void kernel_launch(void* const* d_in, const int* in_sizes, int n_in,
                              void* d_out, int out_size, void* d_ws, size_t ws_size,
                              hipStream_t stream) {
    const float* x     = (const float*)d_in[0];
    const int*   pw    = (const int*)d_in[1];
    const float* norms = (const float*)d_in[2];
    const float* s1    = (const float*)d_in[3];
    const float* s2    = (const float*)d_in[4];
    const float* cent  = (const float*)d_in[5];
    const float* bias  = (const float*)d_in[6];
    float* out = (float*)d_out;

    size_t needX = (size_t)MROWS * IN_DIM * 2;    // 128 MB
    size_t needW = (size_t)OUT_DIM * IN_DIM * 2;  //  32 MB
    if (ws_size < needX + needW) return;

    unsigned short* Xb = (unsigned short*)d_ws;
    unsigned short* Wb = (unsigned short*)((char*)d_ws + needX);

    convert_x<<<2048, 256, 0, stream>>>(x, Xb, MROWS * IN_DIM / 8);
    decode_w<<<(OUT_DIM * 32) / 4, 256, 0, stream>>>(pw, norms, s1, s2, cent, Wb);
    gemm_bf16<<<(MROWS / 256) * (OUT_DIM / 256), 512, 0, stream>>>(Xb, Wb, bias, out);
}

// Round 6
// 656.574 us; speedup vs baseline: 1.1464x; 1.0309x over previous
//
#include <hip/hip_runtime.h>
#include <hip/hip_bf16.h>

typedef __attribute__((ext_vector_type(8))) short short8;
typedef __attribute__((ext_vector_type(4))) float floatx4;

#define IN_DIM  4096
#define OUT_DIM 4096
#define MROWS   16384
#define GSIZE   128

template <int N> struct IC { static constexpr int value = N; };

__device__ __forceinline__ unsigned short f2bf(float f) {
    unsigned int u = __builtin_bit_cast(unsigned int, f);
    u = (u + 0x7fffu + ((u >> 16) & 1u)) >> 16;
    return (unsigned short)u;
}

#define GLD16(gsrc, ldst)                                                     \
    __builtin_amdgcn_global_load_lds(                                         \
        (const __attribute__((address_space(1))) unsigned int*)(const void*)(gsrc), \
        (__attribute__((address_space(3))) unsigned int*)(void*)(ldst),       \
        16, 0, 0)

// ---------------------------------------------------------------- convert x
__global__ void convert_x(const float* __restrict__ x,
                          unsigned short* __restrict__ xb, int n8) {
    int stride = gridDim.x * blockDim.x;
    for (int i = blockIdx.x * blockDim.x + threadIdx.x; i < n8; i += stride) {
        const float4* xf = (const float4*)x;
        float4 f0 = xf[2 * i];
        float4 f1 = xf[2 * i + 1];
        union { unsigned short u[8]; uint4 v; } pk;
        pk.u[0] = f2bf(f0.x); pk.u[1] = f2bf(f0.y);
        pk.u[2] = f2bf(f0.z); pk.u[3] = f2bf(f0.w);
        pk.u[4] = f2bf(f1.x); pk.u[5] = f2bf(f1.y);
        pk.u[6] = f2bf(f1.z); pk.u[7] = f2bf(f1.w);
        ((uint4*)xb)[i] = pk.v;
    }
}

// ---------------------------------------------------------------- decode W
__global__ void decode_w(const int* __restrict__ pw,
                         const float* __restrict__ norms,
                         const float* __restrict__ s1,
                         const float* __restrict__ s2,
                         const float* __restrict__ cent,
                         unsigned short* __restrict__ W) {
    int row  = blockIdx.x * 4 + (threadIdx.x >> 6);
    int lane = threadIdx.x & 63;
    float nrm = norms[row];
    int c0 = pw[(size_t)row * GSIZE + lane];
    int c1 = pw[(size_t)row * GSIZE + lane + 64];
    float e0 = cent[c0] * nrm * s2[lane];
    float e1 = cent[c1] * nrm * s2[lane + 64];
#pragma unroll
    for (int it = 0; it < 7; ++it) {
        float a = e0, b = e1;
        e0 = a + b;
        e1 = a - b;
    }
    const float inv = 0.08838834764831845f; // 1/sqrt(128)
    int o = row >> 5, g = row & 31;
    unsigned short* wr = W + (size_t)o * IN_DIM + g * GSIZE;
    wr[lane]      = f2bf(e0 * inv * s1[lane]);
    wr[lane + 64] = f2bf(e1 * inv * s1[lane + 64]);
}

// ---------------------------------------------------------------- GEMM
// m201-faithful 8-phase schedule. 256x256 tile, BK=64, 8 waves (2M x 4N).
// 4 phases/K-tile, each = {ds-reads || 1 half-tile stage} -> barrier ->
// lgkmcnt(0) -> 16 MFMA (one C-quadrant) -> barrier. NO sched_barrier
// (m141: order-pinning regresses). vmcnt(6) once per K-tile at p3.
//
// Quadrants: p0 (m0-3,n0-1) reads b0,b1+a0-3 (12); p1 (m0-3,n2-3) reads
// b2,b3 (4); p2 (m4-7,n0-1) reads a4-7 (8); p3 (m4-7,n2-3) reads 0.
// Regions: A0 = A rows[0,64)u[128,192) (read p0 only), A1 = rows[64,128)
// u[192,256) (read p2 only), B0 = B rows[0,128), B1 = rows[128,256)
// (B read across p0+p1). Stage plan at tile j (BF=j&1):
//   p0: A1(j+1)->BF^1  [A1 of BF^1 last read at p2(j-1); p2 end-bar certifies]
//   p1: A0(j+2)->BF    [A0 read only at p0(j); p0 end-bar certifies]
//   p2: B0(j+2)->BF    [B fully read by p1 end-bar]
//   p3: B1(j+2)->BF; vmcnt(6) leaves exactly {A0,B0,B1}(j+2) outstanding
//       -> A1(j+1)+older landed -> tile j+1 resident; end-bar globalizes.
__global__ __launch_bounds__(512, 2)
void gemm_bf16(const unsigned short* __restrict__ Xg,
               const unsigned short* __restrict__ Wg,
               const float* __restrict__ bias,
               float* __restrict__ out) {
    __shared__ unsigned short As[2][256][64];
    __shared__ unsigned short Bs[2][256][64];

    // bijective XCD swizzle (1024 blocks % 8 == 0); consecutive ids share mt
    int id = (blockIdx.x & 7) * 128 + (blockIdx.x >> 3);
    int mt = id >> 4, nt = id & 15;
    int m0 = mt * 256, n0 = nt * 256;

    int tid  = threadIdx.x;
    int lane = tid & 63;
    int wid  = tid >> 6;
    int wm = wid >> 2, wn = wid & 3;   // wave tile: rows wm*128+, cols wn*64+

    // staging: thread handles 16B phys chunk cp0 of rows sr0 / sr0+64(+128)
    int sr0 = tid >> 3;        // 0..63
    int cp0 = tid & 7;         // physical chunk position
    int sg0 = cp0 ^ (sr0 & 7); // global chunk (inverse swizzle)

// A halves interleaved: h=0 -> rows [0,64)u[128,192) (m-frags 0-3),
//                       h=1 -> rows [64,128)u[192,256) (m-frags 4-7)
#define STG_AH(bufc, h, j) do {                                               \
    const unsigned short* _s =                                                \
        Xg + (size_t)(m0 + (h)*64 + sr0) * IN_DIM + (size_t)(j)*64 + sg0*8;   \
    GLD16(_s,                 &As[bufc][(h)*64 + sr0][cp0 * 8]);              \
    GLD16(_s + 128 * IN_DIM,  &As[bufc][128 + (h)*64 + sr0][cp0 * 8]);        \
  } while (0)
// B halves contiguous: h=0 -> rows [0,128), h=1 -> rows [128,256)
#define STG_BH(bufc, h, j) do {                                               \
    const unsigned short* _s =                                                \
        Wg + (size_t)(n0 + (h)*128 + sr0) * IN_DIM + (size_t)(j)*64 + sg0*8;  \
    GLD16(_s,                &Bs[bufc][(h)*128 + sr0][cp0 * 8]);              \
    GLD16(_s + 64 * IN_DIM,  &Bs[bufc][(h)*128 + sr0 + 64][cp0 * 8]);         \
  } while (0)

    int rl = lane & 15, kc = lane >> 4;
    short8 a_[8][2], b_[4][2];
    floatx4 acc[8][4] = {};

#define LD_A(BFc, m, ks) do {                                                 \
    int row_ = wm * 128 + (m)*16 + rl;                                        \
    a_[m][ks] = *(const short8*)&As[BFc][row_][((((ks)*4 + kc) ^ (row_ & 7)) << 3)]; \
  } while (0)
#define LD_B(BFc, n, ks) do {                                                 \
    int row_ = wn * 64 + (n)*16 + rl;                                         \
    b_[n][ks] = *(const short8*)&Bs[BFc][row_][((((ks)*4 + kc) ^ (row_ & 7)) << 3)]; \
  } while (0)

#define MFMA_Q(mh, nh) do {                                                   \
    __builtin_amdgcn_s_setprio(1);                                            \
    _Pragma("unroll") for (int ks = 0; ks < 2; ++ks) {                        \
      _Pragma("unroll") for (int m = 4*(mh); m < 4*(mh) + 4; ++m) {           \
        _Pragma("unroll") for (int n = 2*(nh); n < 2*(nh) + 2; ++n)           \
          acc[m][n] = __builtin_amdgcn_mfma_f32_16x16x32_bf16(                \
              a_[m][ks], b_[n][ks], acc[m][n], 0, 0, 0);                      \
      }                                                                       \
    }                                                                         \
    __builtin_amdgcn_s_setprio(0);                                            \
  } while (0)

    // ---- prologue: tile0 full (8 loads); A0,B0,B1 of tile1 (6 loads)
    STG_BH(0, 0, 0); STG_BH(0, 1, 0); STG_AH(0, 0, 0); STG_AH(0, 1, 0);
    STG_AH(1, 0, 1); STG_BH(1, 0, 1); STG_BH(1, 1, 1);
    asm volatile("s_waitcnt vmcnt(6)" ::: "memory");  // tile0 resident
    __builtin_amdgcn_s_barrier();

    // MODE: 2 = steady; 1 = j=62 (stage A1(63) only, vmcnt(0)); 0 = j=63
    auto body = [&](int j, auto bfc, auto modec) {
        constexpr int BF   = decltype(bfc)::value;
        constexpr int MODE = decltype(modec)::value;
        // ---- p0: quadrant (m0-3, n0-1); 12 reads; stage A1(j+1)
        LD_B(BF, 0, 0); LD_B(BF, 0, 1); LD_B(BF, 1, 0); LD_B(BF, 1, 1);
        LD_A(BF, 0, 0); LD_A(BF, 0, 1); LD_A(BF, 1, 0); LD_A(BF, 1, 1);
        LD_A(BF, 2, 0); LD_A(BF, 2, 1); LD_A(BF, 3, 0); LD_A(BF, 3, 1);
        if constexpr (MODE >= 1) STG_AH(BF ^ 1, 1, j + 1);
        asm volatile("s_waitcnt lgkmcnt(8)" ::: "memory");
        __builtin_amdgcn_s_barrier();
        asm volatile("s_waitcnt lgkmcnt(0)" ::: "memory");
        MFMA_Q(0, 0);
        __builtin_amdgcn_s_barrier();
        // ---- p1: quadrant (m0-3, n2-3); 4 reads; stage A0(j+2)
        LD_B(BF, 2, 0); LD_B(BF, 2, 1); LD_B(BF, 3, 0); LD_B(BF, 3, 1);
        if constexpr (MODE == 2) STG_AH(BF, 0, j + 2);
        __builtin_amdgcn_s_barrier();
        asm volatile("s_waitcnt lgkmcnt(0)" ::: "memory");
        MFMA_Q(0, 1);
        __builtin_amdgcn_s_barrier();
        // ---- p2: quadrant (m4-7, n0-1); 8 reads; stage B0(j+2)
        LD_A(BF, 4, 0); LD_A(BF, 4, 1); LD_A(BF, 5, 0); LD_A(BF, 5, 1);
        LD_A(BF, 6, 0); LD_A(BF, 6, 1); LD_A(BF, 7, 0); LD_A(BF, 7, 1);
        if constexpr (MODE == 2) STG_BH(BF, 0, j + 2);
        __builtin_amdgcn_s_barrier();
        asm volatile("s_waitcnt lgkmcnt(0)" ::: "memory");
        MFMA_Q(1, 0);
        __builtin_amdgcn_s_barrier();
        // ---- p3: quadrant (m4-7, n2-3); 0 reads; stage B1(j+2); vmcnt
        if constexpr (MODE == 2) {
            STG_BH(BF, 1, j + 2);
            asm volatile("s_waitcnt vmcnt(6)" ::: "memory"); // tile j+1 landed
        } else if constexpr (MODE == 1) {
            asm volatile("s_waitcnt vmcnt(0)" ::: "memory");
        }
        __builtin_amdgcn_s_barrier();
        MFMA_Q(1, 1);
        __builtin_amdgcn_s_barrier();
    };

    for (int j = 0; j < 62; j += 2) {
        body(j,     IC<0>{}, IC<2>{});
        body(j + 1, IC<1>{}, IC<2>{});
    }
    body(62, IC<0>{}, IC<1>{});
    body(63, IC<1>{}, IC<0>{});

    // ---- epilogue: C/D layout col = lane&15, row = (lane>>4)*4 + i
    int q = lane >> 4;
#pragma unroll
    for (int n = 0; n < 4; ++n) {
        int col = n0 + wn * 64 + n * 16 + rl;
        float bv = bias[col];
#pragma unroll
        for (int m = 0; m < 8; ++m) {
#pragma unroll
            for (int i = 0; i < 4; ++i) {
                int row = m0 + wm * 128 + m * 16 + q * 4 + i;
                out[(size_t)row * OUT_DIM + col] = acc[m][n][i] + bv;
            }
        }
    }
#undef STG_AH
#undef STG_BH
#undef LD_A
#undef LD_B
#undef MFMA_Q
}

// ---------------------------------------------------------------- launch
extern "C" void kernel_launch(void* const* d_in, const int* in_sizes, int n_in,
                              void* d_out, int out_size, void* d_ws, size_t ws_size,
                              hipStream_t stream) {
    const float* x     = (const float*)d_in[0];
    const int*   pw    = (const int*)d_in[1];
    const float* norms = (const float*)d_in[2];
    const float* s1    = (const float*)d_in[3];
    const float* s2    = (const float*)d_in[4];
    const float* cent  = (const float*)d_in[5];
    const float* bias  = (const float*)d_in[6];
    float* out = (float*)d_out;

    size_t needX = (size_t)MROWS * IN_DIM * 2;    // 128 MB
    size_t needW = (size_t)OUT_DIM * IN_DIM * 2;  //  32 MB
    if (ws_size < needX + needW) return;

    unsigned short* Xb = (unsigned short*)d_ws;
    unsigned short* Wb = (unsigned short*)((char*)d_ws + needX);

    convert_x<<<2048, 256, 0, stream>>>(x, Xb, MROWS * IN_DIM / 8);
    decode_w<<<(OUT_DIM * 32) / 4, 256, 0, stream>>>(pw, norms, s1, s2, cent, Wb);
    gemm_bf16<<<(MROWS / 256) * (OUT_DIM / 256), 512, 0, stream>>>(Xb, Wb, bias, out);
}